// Round 4
// baseline (511.257 us; speedup 1.0000x reference)
//
#include <hip/hip_runtime.h>
#include <math.h>

namespace {
constexpr int NB   = 256;          // graphs
constexpr int EPG  = 8192;         // edges per graph
constexpr int ETOT = NB * EPG;     // 2,097,152
constexpr int FH   = 64;           // hidden dim
constexpr int NN0  = NB * 512;     // 131072 nodes at full size
}

// ---- scratch (device globals: write-before-read each call, deterministic) ----
__device__ float g_feat[3][(size_t)NN0 * FH];   // rotating node-feature buffers
__device__ float g_xs[NB * 6 * FH];             // jumping-knowledge concat
__device__ int   g_esrc[2][ETOT];               // compacted edges (stage 0/1)
__device__ int   g_edst[2][ETOT];
__device__ int   g_ecnt[2][NB];

// ============================================================================
// Dual matmul: zr = x@Wr ; xl = x@Wl + b   (x: [M,K], W: [K,64], M % 64 == 0)
// ============================================================================
template<int K>
__global__ __launch_bounds__(256)
void mm_dual(const float* __restrict__ xext, int in_idx,
             const float* __restrict__ Wr, const float* __restrict__ Wl,
             const float* __restrict__ bias, int zr_idx, int xl_idx)
{
  __shared__ float xt[64 * K];
  const float* __restrict__ x = (in_idx < 0) ? xext : g_feat[in_idx];
  float* __restrict__ zr = g_feat[zr_idx];
  float* __restrict__ xl = g_feat[xl_idx];
  const int t = threadIdx.x;
  const int rowbase = blockIdx.x * 64;
  const float4* srcv = reinterpret_cast<const float4*>(x + (size_t)rowbase * K);
  float4* dstv = reinterpret_cast<float4*>(xt);
  constexpr int NV = 64 * K / 4;
  #pragma unroll
  for (int i = 0; i < NV / 256; ++i) dstv[t + i * 256] = srcv[t + i * 256];
  __syncthreads();
  const int f  = t & 63;
  const int rg = t >> 6;                 // 4 row-groups x 16 rows
  float accr[16], accl[16];
  #pragma unroll
  for (int r = 0; r < 16; ++r) { accr[r] = 0.f; accl[r] = 0.f; }
  for (int k4 = 0; k4 < K / 4; ++k4) {
    const int kb = k4 * 4;
    const float wr0 = Wr[(kb+0)*64+f], wr1 = Wr[(kb+1)*64+f],
                wr2 = Wr[(kb+2)*64+f], wr3 = Wr[(kb+3)*64+f];
    const float wl0 = Wl[(kb+0)*64+f], wl1 = Wl[(kb+1)*64+f],
                wl2 = Wl[(kb+2)*64+f], wl3 = Wl[(kb+3)*64+f];
    #pragma unroll
    for (int r = 0; r < 16; ++r) {
      const float4 xv = *reinterpret_cast<const float4*>(&xt[(rg*16+r)*K + kb]);
      accr[r] += xv.x*wr0 + xv.y*wr1 + xv.z*wr2 + xv.w*wr3;
      accl[r] += xv.x*wl0 + xv.y*wl1 + xv.z*wl2 + xv.w*wl3;
    }
  }
  const float bv = bias[f];
  #pragma unroll
  for (int r = 0; r < 16; ++r) {
    const int row = rowbase + rg*16 + r;
    zr[(size_t)row*64 + f] = accr[r];
    xl[(size_t)row*64 + f] = accl[r] + bv;
  }
}

// ============================================================================
// Full-size (n=512/graph) mean-aggregation + residual + relu + fused gmp.
//   xout = relu(mean_agg(zr) + xl) ; g_xs[:, xs_off:xs_off+64] = mean(xout)
// One workgroup per graph; CSR built in LDS (histogram+scan+scatter).
// ============================================================================
__global__ __launch_bounds__(1024)
void agg_full(int zr_idx, int xl_idx,
              const int* __restrict__ esrc, const int* __restrict__ edst,
              int out_idx, int xs_off)
{
  __shared__ unsigned int hist[512], bufA[512], bufB[512];
  __shared__ unsigned short csr[EPG];
  __shared__ float red[16][64];
  const float* __restrict__ zr  = g_feat[zr_idx];
  const float* __restrict__ xlb = g_feat[xl_idx];
  float* __restrict__ xout = g_feat[out_idx];
  const int g = blockIdx.x, t = threadIdx.x;
  const int gbase = g * 512, ebase = g * EPG;
  for (int i = t; i < 512; i += 1024) hist[i] = 0;
  __syncthreads();
  for (int e = t; e < EPG; e += 1024)
    atomicAdd(&hist[edst[ebase + e] - gbase], 1u);
  __syncthreads();
  if (t < 512) bufA[t] = hist[t];
  __syncthreads();
  unsigned int *pa = bufA, *pb = bufB;
  for (int off = 1; off < 512; off <<= 1) {      // Hillis-Steele inclusive scan
    if (t < 512) {
      unsigned int v = pa[t];
      if (t >= off) v += pa[t - off];
      pb[t] = v;
    }
    __syncthreads();
    unsigned int* tmp = pa; pa = pb; pb = tmp;
  }
  unsigned int excl = 0;
  if (t < 512) excl = pa[t] - hist[t];
  __syncthreads();
  if (t < 512) { bufA[t] = excl; bufB[t] = excl; }  // bufA = start, bufB = cursor
  __syncthreads();
  for (int e = t; e < EPG; e += 1024) {
    const int sl = esrc[ebase + e] - gbase;
    const int dl = edst[ebase + e] - gbase;
    const unsigned int pos = atomicAdd(&bufB[dl], 1u);
    csr[pos] = (unsigned short)sl;
  }
  __syncthreads();
  const int lane = t & 63, w = t >> 6;            // 16 waves, lane = feature
  float psum = 0.f;
  for (int nd = w; nd < 512; nd += 16) {
    const unsigned int s = bufA[nd], d = hist[nd];
    float acc = 0.f;
    for (unsigned int j = 0; j < d; ++j)
      acc += zr[(size_t)(gbase + csr[s + j]) * 64 + lane];
    float v = acc / (float)(d > 0 ? d : 1) + xlb[(size_t)(gbase + nd)*64 + lane];
    v = fmaxf(v, 0.f);
    xout[(size_t)(gbase + nd)*64 + lane] = v;
    psum += v;
  }
  red[w][lane] = psum;
  __syncthreads();
  if (t < 64) {
    float s = 0.f;
    #pragma unroll
    for (int ww = 0; ww < 16; ++ww) s += red[ww][t];
    g_xs[g*384 + xs_off + t] = s * (1.f/512.f);
  }
}

// ============================================================================
// Small (n=57 or 7) aggregation over compacted edges + fused gmp.
// ============================================================================
template<int NPER>
__global__ __launch_bounds__(256)
void agg_small(int zr_idx, int xl_idx, int stage, int out_idx, int xs_off)
{
  __shared__ unsigned int hist[NPER], sstart[NPER], scur[NPER];
  __shared__ unsigned short csr[EPG];
  __shared__ float red[4][64];
  const float* __restrict__ zr  = g_feat[zr_idx];
  const float* __restrict__ xlb = g_feat[xl_idx];
  float* __restrict__ xout = g_feat[out_idx];
  const int* __restrict__ esrc = g_esrc[stage];
  const int* __restrict__ edst = g_edst[stage];
  const int g = blockIdx.x, t = threadIdx.x;
  const int gbase = g * NPER, ebase = g * EPG;
  const int m = g_ecnt[stage][g];
  if (t < NPER) hist[t] = 0;
  __syncthreads();
  for (int e = t; e < m; e += 256)
    atomicAdd(&hist[edst[ebase + e] - gbase], 1u);
  __syncthreads();
  if (t == 0) {
    unsigned int run = 0;
    for (int i = 0; i < NPER; ++i) { sstart[i] = run; scur[i] = run; run += hist[i]; }
  }
  __syncthreads();
  for (int e = t; e < m; e += 256) {
    const int sl = esrc[ebase + e] - gbase;
    const int dl = edst[ebase + e] - gbase;
    const unsigned int pos = atomicAdd(&scur[dl], 1u);
    csr[pos] = (unsigned short)sl;
  }
  __syncthreads();
  const int lane = t & 63, w = t >> 6;            // 4 waves
  float psum = 0.f;
  for (int nd = w; nd < NPER; nd += 4) {
    const unsigned int s = sstart[nd], d = hist[nd];
    float acc = 0.f;
    for (unsigned int j = 0; j < d; ++j)
      acc += zr[(size_t)(gbase + csr[s + j]) * 64 + lane];
    float v = acc / (float)(d > 0 ? d : 1) + xlb[(size_t)(gbase + nd)*64 + lane];
    v = fmaxf(v, 0.f);
    xout[(size_t)(gbase + nd)*64 + lane] = v;
    psum += v;
  }
  red[w][lane] = psum;
  __syncthreads();
  if (t < 64) {
    float s = red[0][t] + red[1][t] + red[2][t] + red[3][t];
    g_xs[g*384 + xs_off + t] = s * (1.f/(float)NPER);
  }
}

// ============================================================================
// SAG pool: score (scalar gconv via linearity) -> per-graph top-k (bitonic on
// packed (ordered-float, ~idx) keys == jax.lax.top_k semantics) ->
// new_x = x[perm]*tanh(score[perm]) -> edge compaction with remapped ids.
// ============================================================================
template<int NPER, int NPOW2, int KSEL>
__global__ __launch_bounds__(512)
void sag_pool(int in_idx,
              const int* __restrict__ esrc_ext, const int* __restrict__ edst_ext,
              int in_stage,
              const float* __restrict__ wr, const float* __restrict__ wl,
              const float* __restrict__ pb,
              int xnew_idx, int out_stage)
{
  __shared__ float zs[NPER], swl[NPER], sagg[NPER], sdeg[NPER], sscore[NPER];
  __shared__ unsigned long long keys[NPOW2];
  __shared__ short newpos[NPER];
  __shared__ int scnt;
  const float* __restrict__ xin = g_feat[in_idx];
  float* __restrict__ xnew = g_feat[xnew_idx];
  const int* __restrict__ esrc = (in_stage < 0) ? esrc_ext : g_esrc[in_stage];
  const int* __restrict__ edst = (in_stage < 0) ? edst_ext : g_edst[in_stage];
  int* __restrict__ eosrc = g_esrc[out_stage];
  int* __restrict__ eodst = g_edst[out_stage];
  const int g = blockIdx.x, t = threadIdx.x;
  const int gbase = g * NPER, ebase = g * EPG;
  const int m = (in_stage < 0) ? EPG : g_ecnt[in_stage][g];
  const int lane = t & 63, w = t >> 6;            // 8 waves
  const float wrv = wr[lane], wlv = wl[lane];
  for (int nd = w; nd < NPER; nd += 8) {          // per-node dots via shfl reduce
    const float v = xin[(size_t)(gbase + nd)*64 + lane];
    float a = v * wrv, b = v * wlv;
    #pragma unroll
    for (int off = 32; off > 0; off >>= 1) {
      a += __shfl_xor(a, off);
      b += __shfl_xor(b, off);
    }
    if (lane == 0) { zs[nd] = a; swl[nd] = b; }
  }
  if (t < NPER) { sagg[t] = 0.f; sdeg[t] = 0.f; }
  if (t == 0) scnt = 0;
  __syncthreads();
  for (int e = t; e < m; e += 512) {              // scalar message aggregation
    const int sl = esrc[ebase + e] - gbase;
    const int dl = edst[ebase + e] - gbase;
    atomicAdd(&sagg[dl], zs[sl]);
    atomicAdd(&sdeg[dl], 1.f);
  }
  __syncthreads();
  if (t < NPER)
    sscore[t] = sagg[t] / fmaxf(sdeg[t], 1.f) + pb[0] + swl[t];
  __syncthreads();
  if (t < NPOW2) {                                // pack sort keys
    unsigned long long key = 0ull;
    if (t < NPER) {
      unsigned int u = __float_as_uint(sscore[t]);
      u = (u & 0x80000000u) ? ~u : (u | 0x80000000u);   // order-preserving map
      key = ((unsigned long long)u << 32) | (unsigned int)(~(unsigned int)t);
    }
    keys[t] = key;
  }
  __syncthreads();
  for (int kk = 2; kk <= NPOW2; kk <<= 1) {       // bitonic sort, descending
    for (int j = kk >> 1; j > 0; j >>= 1) {
      if (t < NPOW2) {
        const int ixj = t ^ j;
        if (ixj > t) {
          const unsigned long long a = keys[t], bk = keys[ixj];
          const bool up = ((t & kk) == 0);
          if (up ? (a < bk) : (a > bk)) { keys[t] = bk; keys[ixj] = a; }
        }
      }
      __syncthreads();
    }
  }
  if (t < NPER) newpos[t] = -1;
  __syncthreads();
  if (t < KSEL)
    newpos[(int)(~(unsigned int)(keys[t] & 0xffffffffull))] = (short)t;
  __syncthreads();
  for (int r = w; r < KSEL; r += 8) {             // gather selected nodes
    const int old = (int)(~(unsigned int)(keys[r] & 0xffffffffull));
    const float sc = tanhf(sscore[old]);
    xnew[(size_t)(g*KSEL + r)*64 + lane] =
        xin[(size_t)(gbase + old)*64 + lane] * sc;
  }
  for (int e = t; e < m; e += 512) {              // compact surviving edges
    const int sl = esrc[ebase + e] - gbase;
    const int dl = edst[ebase + e] - gbase;
    const int ns = newpos[sl], nd2 = newpos[dl];
    if (ns >= 0 && nd2 >= 0) {
      const int slot = atomicAdd(&scnt, 1);
      eosrc[ebase + slot] = g*KSEL + ns;
      eodst[ebase + slot] = g*KSEL + nd2;
    }
  }
  __syncthreads();
  if (t == 0) g_ecnt[out_stage][g] = scnt;
}

// ============================================================================
// MLP head: h=[B,384] -> relu(h@W1+b1) -> @W2+b2 -> log_softmax
// ============================================================================
__global__ __launch_bounds__(64)
void head(const float* __restrict__ W1, const float* __restrict__ b1,
          const float* __restrict__ W2, const float* __restrict__ b2,
          float* __restrict__ out)
{
  __shared__ float h[384], o1[64], lg[2];
  const int g = blockIdx.x, t = threadIdx.x;
  for (int i = t; i < 384; i += 64) h[i] = g_xs[g*384 + i];
  __syncthreads();
  float acc = b1[t];
  for (int j = 0; j < 384; ++j) acc += h[j] * W1[j*64 + t];
  o1[t] = fmaxf(acc, 0.f);
  __syncthreads();
  if (t < 2) {
    float a2 = b2[t];
    for (int f2 = 0; f2 < 64; ++f2) a2 += o1[f2] * W2[f2*2 + t];
    lg[t] = a2;
  }
  __syncthreads();
  if (t < 2) {
    const float mx = fmaxf(lg[0], lg[1]);
    const float lse = mx + logf(expf(lg[0]-mx) + expf(lg[1]-mx));
    out[g*2 + t] = lg[t] - lse;
  }
}

// ============================================================================
extern "C" void kernel_launch(void* const* d_in, const int* in_sizes, int n_in,
                              void* d_out, int out_size, void* d_ws, size_t ws_size,
                              hipStream_t stream)
{
  (void)in_sizes; (void)n_in; (void)d_ws; (void)ws_size; (void)out_size;
  const float* x    = (const float*)d_in[0];
  const int*   ei   = (const int*)d_in[1];
  const float* c1Wr = (const float*)d_in[2];
  const float* c1Wl = (const float*)d_in[3];
  const float* c1b  = (const float*)d_in[4];
  const float* cWr  = (const float*)d_in[5];
  const float* cWl  = (const float*)d_in[6];
  const float* cb   = (const float*)d_in[7];
  const float* pWr  = (const float*)d_in[8];
  const float* pWl  = (const float*)d_in[9];
  const float* pb   = (const float*)d_in[10];
  const float* l1W  = (const float*)d_in[11];
  const float* l1b  = (const float*)d_in[12];
  const float* l2W  = (const float*)d_in[13];
  const float* l2b  = (const float*)d_in[14];
  float* out = (float*)d_out;
  const int* esrc = ei;
  const int* edst = ei + ETOT;

  // conv1 (160->64) + relu, xs[0]
  mm_dual<160><<<NN0/64, 256, 0, stream>>>(x, -1, c1Wr, c1Wl, c1b, 0, 1);
  agg_full<<<NB, 1024, 0, stream>>>(0, 1, esrc, edst, 1, 0);
  // convs[0] + relu, xs[1]
  mm_dual<64><<<NN0/64, 256, 0, stream>>>(nullptr, 1, cWr, cWl, cb, 0, 2);
  agg_full<<<NB, 1024, 0, stream>>>(0, 2, esrc, edst, 2, 64);
  // pool0: 512 -> 57
  sag_pool<512,512,57><<<NB, 512, 0, stream>>>(2, esrc, edst, -1, pWr, pWl, pb, 0, 0);
  // convs[1] + relu, xs[2]   (14592 rows = 228*64)
  mm_dual<64><<<228, 256, 0, stream>>>(nullptr, 0, cWr+4096, cWl+4096, cb+64, 1, 2);
  agg_small<57><<<NB, 256, 0, stream>>>(1, 2, 0, 2, 128);
  // convs[2] + relu, xs[3]
  mm_dual<64><<<228, 256, 0, stream>>>(nullptr, 2, cWr+8192, cWl+8192, cb+128, 1, 0);
  agg_small<57><<<NB, 256, 0, stream>>>(1, 0, 0, 0, 192);
  // pool1: 57 -> 7
  sag_pool<57,64,7><<<NB, 512, 0, stream>>>(0, nullptr, nullptr, 0, pWr+64, pWl+64, pb+1, 1, 1);
  // convs[3] + relu, xs[4]   (1792 rows = 28*64)
  mm_dual<64><<<28, 256, 0, stream>>>(nullptr, 1, cWr+12288, cWl+12288, cb+192, 0, 2);
  agg_small<7><<<NB, 256, 0, stream>>>(0, 2, 1, 2, 256);
  // convs[4] + relu, xs[5]
  mm_dual<64><<<28, 256, 0, stream>>>(nullptr, 2, cWr+16384, cWl+16384, cb+256, 0, 1);
  agg_small<7><<<NB, 256, 0, stream>>>(0, 1, 1, 1, 320);
  // head
  head<<<NB, 64, 0, stream>>>(l1W, l1b, l2W, l2b, out);
}